// Round 5
// baseline (233.903 us; speedup 1.0000x reference)
//
#include <hip/hip_runtime.h>
#include <math.h>

// Problem constants (fixed shapes per reference)
constexpr int NPB = 15;   // NUM_PROB_BINS
constexpr int NC  = 8;    // NUM_CLASSES
constexpr int NNB = 9;    // NUM_NEIGHBOR_CLASSES (3x3)
constexpr int Bn  = 16;
constexpr int Hc  = 512;
constexpr int Wc  = 512;

// Tile: 64x32 outputs per 1024-thread block, +1 halo ring.
// Halo redundancy 66*34/2048 = 1.096.
// LDS = 71808 + 4320 = 76128 B -> 2 blocks/CU -> 32 waves/CU.
constexpr int TX = 64, TY = 32;
constexpr int HX = TX + 2;  // 66
constexpr int HY = TY + 2;  // 34
constexpr int NT = 1024;
constexpr int GX = Wc / TX;           // 8
constexpr int GY = Hc / TY;           // 16
constexpr int NBLK = GX * GY * Bn;    // 2048
constexpr int NHALO = HX * HY;        // 2244

typedef float f32x2 __attribute__((ext_vector_type(2)));

// fp32-correctly-rounded-almost-always exp for d in [-90, 0].
// Half-octave reduction, single constant (|k|<=260 -> kd*ulp(ln2/2) < 6e-15
// rel). Degree-8 Taylor on |r| <= ln2/4: rel err 3.7e-13 -> non-CR fraction
// ~1e-5 -> expected bin flips ~1e-4 over all 40M calls. Validated: absmax
// stayed at the bf16 comparison floor (no flips). NUMERICS FROZEN.
__device__ __forceinline__ float exp_f32_cr(float df) {
    const double d = (double)df;
    double t  = d * 2.8853900817779268;            // 2*log2(e)
    double kd = rint(t);
    int    k  = (int)kd;
    double r  = fma(kd, -0.34657359027997265, d);  // nearest-double -(ln2/2)
    double p = 2.48015873015873016e-5;             // 1/8!
    p = fma(p, r, 1.98412698412698413e-4);
    p = fma(p, r, 1.38888888888888889e-3);
    p = fma(p, r, 8.33333333333333333e-3);
    p = fma(p, r, 4.16666666666666666e-2);
    p = fma(p, r, 1.66666666666666667e-1);
    p = fma(p, r, 0.5);
    p = fma(p, r, 1.0);
    p = fma(p, r, 1.0);
    double v = (k & 1) ? p * 1.4142135623730951 : p;
    // ldexp by k>>1 via exponent add (v in [0.7,1.5], stays normal)
    long long bits = __double_as_longlong(v) + ((long long)(k >> 1) << 52);
    return (float)__longlong_as_double(bits);
}

// Reciprocal to ~1 ulp of double: rcp_f32 seed + 2 fp64 Newton iters.
// fl32(x * rcp64(s)) != fl32(x/s) with probability ~2^-29 — no bin flips.
// NUMERICS FROZEN.
__device__ __forceinline__ double rcp64(float s) {
    double dS = (double)s;
    double r  = (double)__builtin_amdgcn_rcpf(s);
    r = r * fma(-dS, r, 2.0);
    r = r * fma(-dS, r, 2.0);
    return r;
}

__global__ __launch_bounds__(NT, 8)  // 8 waves/EU -> 2 blocks/CU, VGPR cap 64
void nectar_kernel(const float* __restrict__ logits,
                   const float* __restrict__ vf,
                   float* __restrict__ out)
{
    __shared__ __align__(16) float sP[NC][HY][HX];  // halo softmax probs: 71808 B
    __shared__ float sVF[NC * NNB * NPB];           // calibration table:   4320 B
    // total 76128 B -> 2 blocks/CU, 32 waves/CU

    const int tid = threadIdx.x;

    // XCD swizzle: each XCD owns 32 consecutive semantic tiles (a 512x128
    // band of one image) so halo re-reads hit that XCD's own L2.
    const int h    = blockIdx.x;            // 0..2047
    const int sg   = h >> 8;                // supergroup of 256
    const int xcd  = h & 7;
    const int slot = (h >> 3) & 31;
    const int sem  = (sg << 8) + (xcd << 5) + slot;

    const int bx = sem & (GX - 1);
    const int by = (sem >> 3) & (GY - 1);
    const int b  = sem >> 7;
    const int x0 = bx * TX;
    const int y0 = by * TY;

    const size_t plane = (size_t)Hc * Wc;
    const float* src = logits + (size_t)b * NC * plane;

    // Stage the calibration table (1080 floats; threads 0..1079, one each).
    if (tid < NC * NNB * NPB) sVF[tid] = vf[tid];

    // ---- Phase 1: softmax for every halo pixel.
    // Task i covers halo pixel (ly,lx) = (i/66, i%66). Thread handles
    // i = tid, tid+1024 and, for tid<196, i = tid+2048.
    // All loads use SGPR base (src + c*plane, block-uniform) + one 32-bit
    // per-lane pixel offset -> no per-lane 64-bit address chains.
    // All loads issued up front (one exposed memory latency, loads for
    // task 1/2 retire under task-0 compute).
    int ly_[3], lx_[3];
    bool img_[3];
    unsigned voff_[3];
    const bool has2 = tid < (NHALO - 2 * NT);   // tid < 196

    #pragma unroll
    for (int t = 0; t < 3; t++) {
        const int i  = tid + t * NT;
        const int ly = (int)((unsigned)i / (unsigned)HX);
        const int lx = i - ly * HX;
        const int gy = y0 + ly - 1;
        const int gx = x0 + lx - 1;
        ly_[t]  = ly;
        lx_[t]  = lx;
        img_[t] = ((unsigned)gy < (unsigned)Hc) && ((unsigned)gx < (unsigned)Wc);
        const int gyc = gy < 0 ? 0 : (gy > Hc - 1 ? Hc - 1 : gy);
        const int gxc = gx < 0 ? 0 : (gx > Wc - 1 ? Wc - 1 : gx);
        voff_[t] = (unsigned)(gyc * Wc + gxc);
    }

    float v0[NC], v1[NC], v2[NC];
    #pragma unroll
    for (int c = 0; c < NC; c++) {
        const float* bc = src + (size_t)c * plane;   // uniform (SGPR) base
        v0[c] = bc[voff_[0]];
        v1[c] = bc[voff_[1]];
    }
    if (has2) {
        #pragma unroll
        for (int c = 0; c < NC; c++) {
            const float* bc = src + (size_t)c * plane;
            v2[c] = bc[voff_[2]];
        }
    }

    // Tasks 0 and 1 INTERLEAVED (independent chains -> 2x fp64 ILP).
    // Each task's own fp32/fp64 op ORDER is byte-identical to the
    // validated pipeline (fmax chain, exp_f32_cr, sequential sum, rcp64,
    // per-class double-mul). OOB pixels: rS masked to 0.0 -> all 8
    // products are +0.0 exactly (reduce_window zero-pad semantics).
    {
        float m0 = v0[0], m1 = v1[0];
        #pragma unroll
        for (int c = 1; c < NC; c++) { m0 = fmaxf(m0, v0[c]); m1 = fmaxf(m1, v1[c]); }
        float S0 = 0.0f, S1 = 0.0f;
        #pragma unroll
        for (int c = 0; c < NC; c++) {
            v0[c] = exp_f32_cr(v0[c] - m0);
            v1[c] = exp_f32_cr(v1[c] - m1);
            S0 = S0 + v0[c];                // sequential accumulation (order sacred)
            S1 = S1 + v1[c];
        }
        double r0 = rcp64(S0);
        double r1 = rcp64(S1);
        r0 = img_[0] ? r0 : 0.0;
        r1 = img_[1] ? r1 : 0.0;
        #pragma unroll
        for (int c = 0; c < NC; c++) {
            sP[c][ly_[0]][lx_[0]] = (float)((double)v0[c] * r0);
            sP[c][ly_[1]][lx_[1]] = (float)((double)v1[c] * r1);
        }
    }
    if (has2) {
        float m = v2[0];
        #pragma unroll
        for (int c = 1; c < NC; c++) m = fmaxf(m, v2[c]);
        float S = 0.0f;
        #pragma unroll
        for (int c = 0; c < NC; c++) { v2[c] = exp_f32_cr(v2[c] - m); S = S + v2[c]; }
        double rS = rcp64(S);
        rS = img_[2] ? rS : 0.0;
        #pragma unroll
        for (int c = 0; c < NC; c++)
            sP[c][ly_[2]][lx_[2]] = (float)((double)v2[c] * rS);
    }
    __syncthreads();

    // ---- Phase 2: each thread -> 2 horizontally adjacent outputs.
    // lx2 even + row stride 66 dwords (even) -> all window reads are
    // 8B-aligned f32x2 (ds_read_b64), output stores are dwordx2.
    const int lx2 = (tid & 31) * 2;         // 0,2,..,62
    const int oy  = tid >> 5;               // 0..31
    const int gx2 = x0 + lx2;
    const int gy  = y0 + oy;

    const double C9 = 0.1111111111111111111;    // nearest double to 1/9

    float calL[NC], calR[NC];
    float s0 = 0.0f, s1 = 0.0f;
    #pragma unroll
    for (int c = 0; c < NC; c++) {
        const float* base = &sP[c][oy][lx2];    // halo cols lx2..lx2+3, rows oy..oy+2
        f32x2 u0 = *(const f32x2*)(base);
        f32x2 w0 = *(const f32x2*)(base + 2);
        f32x2 u1 = *(const f32x2*)(base + HX);
        f32x2 w1 = *(const f32x2*)(base + HX + 2);
        f32x2 u2 = *(const f32x2*)(base + 2 * HX);
        f32x2 w2 = *(const f32x2*)(base + 2 * HX + 2);
        // Strict left-to-right sequential add chains (row-major (dy,dx)
        // order) — reassociation would flip bins, order is sacred.
        // Left output window: cols {0,1,2}; right output: cols {1,2,3}.
        float a0 = ((((((((u0.x + u0.y) + w0.x) + u1.x) + u1.y) + w1.x) + u2.x) + u2.y) + w2.x);
        float a1 = ((((((((u0.y + w0.x) + w0.y) + u1.y) + w1.x) + w1.y) + u2.y) + w2.x) + w2.y);

        float nm0 = (float)((double)a0 * C9);   // fl32(a/9) via double mul
        float nm1 = (float)((double)a1 * C9);
        int lb0 = (int)(nm0 * 9.0f);            // trunc == floor (nm >= 0)
        int lb1 = (int)(nm1 * 9.0f);
        lb0 = lb0 > NNB - 1 ? NNB - 1 : lb0;
        lb1 = lb1 > NNB - 1 ? NNB - 1 : lb1;
        int pb0 = (int)(u1.y * 15.0f);          // center of left window
        int pb1 = (int)(w1.x * 15.0f);          // center of right window
        pb0 = pb0 > NPB - 1 ? NPB - 1 : pb0;
        pb1 = pb1 > NPB - 1 ? NPB - 1 : pb1;
        calL[c] = sVF[(c * NNB + lb0) * NPB + pb0];
        calR[c] = sVF[(c * NNB + lb1) * NPB + pb1];
        s0 = s0 + calL[c];                      // sequential class sum
        s1 = s1 + calR[c];
    }
    if (s0 == 0.0f) s0 = 1.0f;
    if (s1 == 0.0f) s1 = 1.0f;

    // Final normalize is NOT bin-critical (bf16-floor comparison): fp32
    // rcp + 1 Newton, rel err ~1e-7 << threshold.
    float q0 = __builtin_amdgcn_rcpf(s0);
    q0 = q0 * fmaf(-s0, q0, 2.0f);
    float q1 = __builtin_amdgcn_rcpf(s1);
    q1 = q1 * fmaf(-s1, q1, 2.0f);

    // Nontemporal stores (write-once/never-read output — don't evict the
    // L3-resident logits). SGPR base per class + one 32-bit voffset.
    const unsigned voff_out = (unsigned)(gy * Wc + gx2);
    #pragma unroll
    for (int c = 0; c < NC; c++) {
        float* oc = out + ((size_t)b * NC + (size_t)c) * plane;  // uniform base
        f32x2 o;
        o.x = calL[c] * q0;
        o.y = calR[c] * q1;
        __builtin_nontemporal_store(o, (f32x2*)(oc + voff_out));
    }
}

extern "C" void kernel_launch(void* const* d_in, const int* in_sizes, int n_in,
                              void* d_out, int out_size, void* d_ws, size_t ws_size,
                              hipStream_t stream) {
    const float* logits = (const float*)d_in[0];
    const float* vf     = (const float*)d_in[1];
    float* out          = (float*)d_out;

    nectar_kernel<<<dim3(NBLK), dim3(NT), 0, stream>>>(logits, vf, out);
}

// Round 6
// 227.558 us; speedup vs baseline: 1.0279x; 1.0279x over previous
//
#include <hip/hip_runtime.h>
#include <math.h>

// Problem constants (fixed shapes per reference)
constexpr int NPB = 15;   // NUM_PROB_BINS
constexpr int NC  = 8;    // NUM_CLASSES
constexpr int NNB = 9;    // NUM_NEIGHBOR_CLASSES (3x3)
constexpr int Bn  = 16;
constexpr int Hc  = 512;
constexpr int Wc  = 512;

// Tile: 64x32 outputs per 1024-thread block, +1 halo ring.
// Halo redundancy 66*34/2048 = 1.096.
// LDS = 71808 + 4320 = 76128 B -> 2 blocks/CU -> 32 waves/CU.
constexpr int TX = 64, TY = 32;
constexpr int HX = TX + 2;  // 66
constexpr int HY = TY + 2;  // 34
constexpr int NT = 1024;
constexpr int GX = Wc / TX;           // 8
constexpr int GY = Hc / TY;           // 16
constexpr int NBLK = GX * GY * Bn;    // 2048
constexpr int NHALO = HX * HY;        // 2244

typedef float f32x2 __attribute__((ext_vector_type(2)));

// 4-wide step-interleaved fp32-correctly-rounded exp (d in [-90,0]).
// PER-CLASS OP SEQUENCE IS BIT-IDENTICAL to the validated exp_f32_cr
// (half-octave reduction, degree-8 Horner in fp64, sqrt2 fixup, exponent
// add). Only the INSTRUCTION INTERLEAVING across the 4 independent lanes
// changes — each coefficient step is 4 independent fp64 FMAs, so the
// scheduler's natural order hides fp64 latency without needing cross-task
// ILP (which R2/R5 showed it refuses to create). NUMERICS FROZEN.
__device__ __forceinline__ void exp4_cr(const float* a, float* o) {
    double r[4], p[4];
    int    k[4];
    #pragma unroll
    for (int j = 0; j < 4; j++) {
        const double d = (double)a[j];
        double kd = rint(d * 2.8853900817779268);      // 2*log2(e)
        k[j] = (int)kd;
        r[j] = fma(kd, -0.34657359027997265, d);       // nearest-double -(ln2/2)
        p[j] = 2.48015873015873016e-5;                 // 1/8!
    }
    #pragma unroll
    for (int j = 0; j < 4; j++) p[j] = fma(p[j], r[j], 1.98412698412698413e-4);
    #pragma unroll
    for (int j = 0; j < 4; j++) p[j] = fma(p[j], r[j], 1.38888888888888889e-3);
    #pragma unroll
    for (int j = 0; j < 4; j++) p[j] = fma(p[j], r[j], 8.33333333333333333e-3);
    #pragma unroll
    for (int j = 0; j < 4; j++) p[j] = fma(p[j], r[j], 4.16666666666666666e-2);
    #pragma unroll
    for (int j = 0; j < 4; j++) p[j] = fma(p[j], r[j], 1.66666666666666667e-1);
    #pragma unroll
    for (int j = 0; j < 4; j++) p[j] = fma(p[j], r[j], 0.5);
    #pragma unroll
    for (int j = 0; j < 4; j++) p[j] = fma(p[j], r[j], 1.0);
    #pragma unroll
    for (int j = 0; j < 4; j++) p[j] = fma(p[j], r[j], 1.0);
    #pragma unroll
    for (int j = 0; j < 4; j++) {
        double v = (k[j] & 1) ? p[j] * 1.4142135623730951 : p[j];
        long long bits = __double_as_longlong(v) + ((long long)(k[j] >> 1) << 52);
        o[j] = (float)__longlong_as_double(bits);
    }
}

// Reciprocal to ~1 ulp of double: rcp_f32 seed + 2 fp64 Newton iters.
// fl32(x * rcp64(s)) != fl32(x/s) with probability ~2^-29 — no bin flips.
// NUMERICS FROZEN.
__device__ __forceinline__ double rcp64(float s) {
    double dS = (double)s;
    double r  = (double)__builtin_amdgcn_rcpf(s);
    r = r * fma(-dS, r, 2.0);
    r = r * fma(-dS, r, 2.0);
    return r;
}

__global__ __launch_bounds__(NT, 8)  // 8 waves/EU -> 2 blocks/CU, VGPR cap 64
void nectar_kernel(const float* __restrict__ logits,
                   const float* __restrict__ vf,
                   float* __restrict__ out)
{
    __shared__ __align__(16) float sP[NC][HY][HX];  // halo softmax probs: 71808 B
    __shared__ float sVF[NC * NNB * NPB];           // calibration table:   4320 B
    // total 76128 B -> 2 blocks/CU, 32 waves/CU

    const int tid = threadIdx.x;

    // XCD swizzle: each XCD owns 32 consecutive semantic tiles (a 512x128
    // band of one image) so halo re-reads hit that XCD's own L2.
    const int h    = blockIdx.x;            // 0..2047
    const int sg   = h >> 8;                // supergroup of 256
    const int xcd  = h & 7;
    const int slot = (h >> 3) & 31;
    const int sem  = (sg << 8) + (xcd << 5) + slot;

    const int bx = sem & (GX - 1);
    const int by = (sem >> 3) & (GY - 1);
    const int b  = sem >> 7;
    const int x0 = bx * TX;
    const int y0 = by * TY;

    const size_t plane = (size_t)Hc * Wc;
    const float* src = logits + (size_t)b * NC * plane;

    // Stage the calibration table (1080 floats; threads 0..1079, one each).
    if (tid < NC * NNB * NPB) sVF[tid] = vf[tid];

    // ---- Phase 1: softmax for every halo pixel.
    // Task i covers halo pixel (ly,lx) = (i/66, i%66). Thread handles
    // i = tid, tid+1024 and, for tid<196, i = tid+2048.
    // Loads use SGPR base (src + c*plane, block-uniform) + 32-bit lane
    // offset. Tasks 0/1 loads issued up front; task-2 loads issued after
    // task-0 compute (they retire under task-1's softmax) to keep peak
    // register pressure under the 64-VGPR cap.
    int ly_[3], lx_[3];
    bool img_[3];
    unsigned voff_[3];
    const bool has2 = tid < (NHALO - 2 * NT);   // tid < 196

    #pragma unroll
    for (int t = 0; t < 3; t++) {
        const int i  = tid + t * NT;
        const int ly = (int)((unsigned)i / (unsigned)HX);
        const int lx = i - ly * HX;
        const int gy = y0 + ly - 1;
        const int gx = x0 + lx - 1;
        ly_[t]  = ly;
        lx_[t]  = lx;
        img_[t] = ((unsigned)gy < (unsigned)Hc) && ((unsigned)gx < (unsigned)Wc);
        const int gyc = gy < 0 ? 0 : (gy > Hc - 1 ? Hc - 1 : gy);
        const int gxc = gx < 0 ? 0 : (gx > Wc - 1 ? Wc - 1 : gx);
        voff_[t] = (unsigned)(gyc * Wc + gxc);
    }

    float v0[NC], v1[NC];
    #pragma unroll
    for (int c = 0; c < NC; c++) {
        const float* bc = src + (size_t)c * plane;   // uniform (SGPR) base
        v0[c] = bc[voff_[0]];
        v1[c] = bc[voff_[1]];
    }

    // ---- Task 0
    {
        float m = v0[0];
        #pragma unroll
        for (int c = 1; c < NC; c++) m = fmaxf(m, v0[c]);
        float d[NC], e[NC];
        #pragma unroll
        for (int c = 0; c < NC; c++) d[c] = v0[c] - m;
        exp4_cr(d, e);            // classes 0..3, step-interleaved
        exp4_cr(d + 4, e + 4);    // classes 4..7
        float S = 0.0f;
        #pragma unroll
        for (int c = 0; c < NC; c++) S = S + e[c];   // sequential (order sacred)
        double rS = rcp64(S);
        rS = img_[0] ? rS : 0.0;  // OOB -> exact +0.0 products (zero-pad)
        #pragma unroll
        for (int c = 0; c < NC; c++)
            sP[c][ly_[0]][lx_[0]] = (float)((double)e[c] * rS);
    }

    // Issue task-2 loads now: they retire under task-1's softmax.
    float v2[NC];
    if (has2) {
        #pragma unroll
        for (int c = 0; c < NC; c++) {
            const float* bc = src + (size_t)c * plane;
            v2[c] = bc[voff_[2]];
        }
    }

    // ---- Task 1
    {
        float m = v1[0];
        #pragma unroll
        for (int c = 1; c < NC; c++) m = fmaxf(m, v1[c]);
        float d[NC], e[NC];
        #pragma unroll
        for (int c = 0; c < NC; c++) d[c] = v1[c] - m;
        exp4_cr(d, e);
        exp4_cr(d + 4, e + 4);
        float S = 0.0f;
        #pragma unroll
        for (int c = 0; c < NC; c++) S = S + e[c];
        double rS = rcp64(S);
        rS = img_[1] ? rS : 0.0;
        #pragma unroll
        for (int c = 0; c < NC; c++)
            sP[c][ly_[1]][lx_[1]] = (float)((double)e[c] * rS);
    }

    // ---- Task 2 (196 threads)
    if (has2) {
        float m = v2[0];
        #pragma unroll
        for (int c = 1; c < NC; c++) m = fmaxf(m, v2[c]);
        float d[NC], e[NC];
        #pragma unroll
        for (int c = 0; c < NC; c++) d[c] = v2[c] - m;
        exp4_cr(d, e);
        exp4_cr(d + 4, e + 4);
        float S = 0.0f;
        #pragma unroll
        for (int c = 0; c < NC; c++) S = S + e[c];
        double rS = rcp64(S);
        rS = img_[2] ? rS : 0.0;
        #pragma unroll
        for (int c = 0; c < NC; c++)
            sP[c][ly_[2]][lx_[2]] = (float)((double)e[c] * rS);
    }
    __syncthreads();

    // ---- Phase 2: each thread -> 2 horizontally adjacent outputs.
    // lx2 even + row stride 66 dwords (even) -> all window reads are
    // 8B-aligned f32x2 (ds_read_b64), output stores are dwordx2.
    const int lx2 = (tid & 31) * 2;         // 0,2,..,62
    const int oy  = tid >> 5;               // 0..31
    const int gx2 = x0 + lx2;
    const int gy  = y0 + oy;

    const double C9 = 0.1111111111111111111;    // nearest double to 1/9

    float calL[NC], calR[NC];
    float s0 = 0.0f, s1 = 0.0f;
    #pragma unroll
    for (int c = 0; c < NC; c++) {
        const float* base = &sP[c][oy][lx2];    // halo cols lx2..lx2+3, rows oy..oy+2
        f32x2 u0 = *(const f32x2*)(base);
        f32x2 w0 = *(const f32x2*)(base + 2);
        f32x2 u1 = *(const f32x2*)(base + HX);
        f32x2 w1 = *(const f32x2*)(base + HX + 2);
        f32x2 u2 = *(const f32x2*)(base + 2 * HX);
        f32x2 w2 = *(const f32x2*)(base + 2 * HX + 2);
        // Strict left-to-right sequential add chains (row-major (dy,dx)
        // order) — reassociation would flip bins, order is sacred.
        // Left output window: cols {0,1,2}; right output: cols {1,2,3}.
        float a0 = ((((((((u0.x + u0.y) + w0.x) + u1.x) + u1.y) + w1.x) + u2.x) + u2.y) + w2.x);
        float a1 = ((((((((u0.y + w0.x) + w0.y) + u1.y) + w1.x) + w1.y) + u2.y) + w2.x) + w2.y);

        float nm0 = (float)((double)a0 * C9);   // fl32(a/9) via double mul
        float nm1 = (float)((double)a1 * C9);
        int lb0 = (int)(nm0 * 9.0f);            // trunc == floor (nm >= 0)
        int lb1 = (int)(nm1 * 9.0f);
        lb0 = lb0 > NNB - 1 ? NNB - 1 : lb0;
        lb1 = lb1 > NNB - 1 ? NNB - 1 : lb1;
        int pb0 = (int)(u1.y * 15.0f);          // center of left window
        int pb1 = (int)(w1.x * 15.0f);          // center of right window
        pb0 = pb0 > NPB - 1 ? NPB - 1 : pb0;
        pb1 = pb1 > NPB - 1 ? NPB - 1 : pb1;
        calL[c] = sVF[(c * NNB + lb0) * NPB + pb0];
        calR[c] = sVF[(c * NNB + lb1) * NPB + pb1];
        s0 = s0 + calL[c];                      // sequential class sum
        s1 = s1 + calR[c];
    }
    if (s0 == 0.0f) s0 = 1.0f;
    if (s1 == 0.0f) s1 = 1.0f;

    // Final normalize is NOT bin-critical (bf16-floor comparison): fp32
    // rcp + 1 Newton, rel err ~1e-7 << threshold.
    float q0 = __builtin_amdgcn_rcpf(s0);
    q0 = q0 * fmaf(-s0, q0, 2.0f);
    float q1 = __builtin_amdgcn_rcpf(s1);
    q1 = q1 * fmaf(-s1, q1, 2.0f);

    // Nontemporal stores (write-once/never-read output — don't evict the
    // L3-resident logits). SGPR base per class + one 32-bit voffset.
    const unsigned voff_out = (unsigned)(gy * Wc + gx2);
    #pragma unroll
    for (int c = 0; c < NC; c++) {
        float* oc = out + ((size_t)b * NC + (size_t)c) * plane;  // uniform base
        f32x2 o;
        o.x = calL[c] * q0;
        o.y = calR[c] * q1;
        __builtin_nontemporal_store(o, (f32x2*)(oc + voff_out));
    }
}

extern "C" void kernel_launch(void* const* d_in, const int* in_sizes, int n_in,
                              void* d_out, int out_size, void* d_ws, size_t ws_size,
                              hipStream_t stream) {
    const float* logits = (const float*)d_in[0];
    const float* vf     = (const float*)d_in[1];
    float* out          = (float*)d_out;

    nectar_kernel<<<dim3(NBLK), dim3(NT), 0, stream>>>(logits, vf, out);
}